// Round 1
// baseline (238.858 us; speedup 1.0000x reference)
//
#include <hip/hip_runtime.h>
#include <math.h>

#define BATCH   4096
#define DIM     1024
#define NGROUPS 1024
#define INV_T   10.0f
#define RANK_W  0.1f
#define SCORE_W 0.01f

// fused GEMM tiling
#define BI   128   // rows (q) per block
#define BJ   256   // cols (a) per block
#define KC   32    // k-chunk per stage (one MFMA k-step)
#define LDSP 40    // padded LDS row stride in bf16 elems (32 data + 8 pad)

typedef float  floatx4 __attribute__((ext_vector_type(4)));
typedef __bf16 bf16x8  __attribute__((ext_vector_type(8)));
typedef __bf16 bf16x4  __attribute__((ext_vector_type(4)));

// ---------------------------------------------------------------------------
// Kernel 1: per-group positive weights. One wave per group (1024 waves).
// w_j = exp(-0.1*rank_j) * exp(0.01*norm_j) / wsum(group)
// ---------------------------------------------------------------------------
__global__ __launch_bounds__(256) void compute_w_kernel(
    const int* __restrict__ qid, const float* __restrict__ ranks,
    const float* __restrict__ scores, float* __restrict__ w)
{
    const int g    = blockIdx.x * 4 + (threadIdx.x >> 6);
    const int lane = threadIdx.x & 63;

    float gmax = -INFINITY, gmin = INFINITY;
    for (int t = 0; t < BATCH / 64; ++t) {
        int j = t * 64 + lane;
        if (qid[j] == g) {
            float s = scores[j];
            gmax = fmaxf(gmax, s);
            gmin = fminf(gmin, s);
        }
    }
    #pragma unroll
    for (int d = 1; d < 64; d <<= 1) {
        gmax = fmaxf(gmax, __shfl_xor(gmax, d, 64));
        gmin = fminf(gmin, __shfl_xor(gmin, d, 64));
    }
    const float denom = gmax - gmin;

    float wsum = 0.f;
    for (int t = 0; t < BATCH / 64; ++t) {
        int j = t * 64 + lane;
        if (qid[j] == g) {
            float norm = (denom > 0.f) ? (scores[j] - gmin) / denom : 0.f;
            wsum += expf(-RANK_W * ranks[j]) * expf(SCORE_W * norm);
        }
    }
    #pragma unroll
    for (int d = 1; d < 64; d <<= 1) wsum += __shfl_xor(wsum, d, 64);

    const float inv = (wsum > 0.f) ? 1.f / wsum : 0.f;
    for (int t = 0; t < BATCH / 64; ++t) {
        int j = t * 64 + lane;
        if (qid[j] == g) {
            float norm = (denom > 0.f) ? (scores[j] - gmin) / denom : 0.f;
            w[j] = expf(-RANK_W * ranks[j]) * expf(SCORE_W * norm) * inv;
        }
    }
}

// ---------------------------------------------------------------------------
// Kernel 2: fused sim = (Q A^T)/T with online per-row (max, sumexp,
// group-weighted sum, argmax). bf16 hi/lo split -> 3 MFMA passes for
// near-fp32 sim precision. Partials per (row, 64-col slice) to ws.
// ---------------------------------------------------------------------------
__device__ __forceinline__ void split4(const float4 v, bf16x4& h, bf16x4& l)
{
    h[0] = (__bf16)v.x; l[0] = (__bf16)(v.x - (float)h[0]);
    h[1] = (__bf16)v.y; l[1] = (__bf16)(v.y - (float)h[1]);
    h[2] = (__bf16)v.z; l[2] = (__bf16)(v.z - (float)h[2]);
    h[3] = (__bf16)v.w; l[3] = (__bf16)(v.w - (float)h[3]);
}

__global__ __launch_bounds__(1024) void fused_simloss_kernel(
    const float* __restrict__ Q, const float* __restrict__ A,
    const int* __restrict__ qid, const float* __restrict__ w,
    float* __restrict__ Pm, float* __restrict__ Pl, float* __restrict__ Ps,
    float* __restrict__ Pbv, int* __restrict__ Pbi)
{
    __shared__ __bf16 sQh[BI * LDSP];
    __shared__ __bf16 sQl[BI * LDSP];
    __shared__ __bf16 sAh[BJ * LDSP];
    __shared__ __bf16 sAl[BJ * LDSP];

    const int jb = blockIdx.x, ib = blockIdx.y;
    const int i0 = ib * BI, j0 = jb * BJ;
    const int tid  = threadIdx.x;
    const int wid  = tid >> 6, lane = tid & 63;
    const int wm   = wid >> 2, wn   = wid & 3;   // 4x4 wave grid, tile 32x64
    const int quad = lane >> 4, l16 = lane & 15;

    floatx4 acc[2][4];
    #pragma unroll
    for (int m = 0; m < 2; ++m)
        #pragma unroll
        for (int n = 0; n < 4; ++n)
            #pragma unroll
            for (int c = 0; c < 4; ++c) acc[m][n][c] = 0.f;

    // staging addresses: Q tile = 1024 float4 (1/thread), A tile = 2048 (2/thread)
    const int srow = tid >> 3;            // 0..127
    const int c4   = (tid & 7) * 4;       // 0,4,...,28
    const float* qptr  = Q + (i0 + srow) * DIM + c4;
    const float* aptr0 = A + (j0 + srow) * DIM + c4;
    const float* aptr1 = A + (j0 + srow + 128) * DIM + c4;

    for (int k0 = 0; k0 < DIM; k0 += KC) {
        const float4 qv  = *(const float4*)(qptr + k0);
        const float4 av0 = *(const float4*)(aptr0 + k0);
        const float4 av1 = *(const float4*)(aptr1 + k0);

        __syncthreads();   // previous iteration's LDS reads done
        {
            bf16x4 h, l;
            split4(qv, h, l);
            *(bf16x4*)&sQh[srow * LDSP + c4] = h;
            *(bf16x4*)&sQl[srow * LDSP + c4] = l;
            split4(av0, h, l);
            *(bf16x4*)&sAh[srow * LDSP + c4] = h;
            *(bf16x4*)&sAl[srow * LDSP + c4] = l;
            split4(av1, h, l);
            *(bf16x4*)&sAh[(srow + 128) * LDSP + c4] = h;
            *(bf16x4*)&sAl[(srow + 128) * LDSP + c4] = l;
        }
        __syncthreads();   // writes visible

        bf16x8 qh[2], ql[2];
        #pragma unroll
        for (int m = 0; m < 2; ++m) {
            int r = wm * 32 + m * 16 + l16;
            qh[m] = *(const bf16x8*)&sQh[r * LDSP + quad * 8];
            ql[m] = *(const bf16x8*)&sQl[r * LDSP + quad * 8];
        }
        #pragma unroll
        for (int n = 0; n < 4; ++n) {
            int r = wn * 64 + n * 16 + l16;
            bf16x8 ah = *(const bf16x8*)&sAh[r * LDSP + quad * 8];
            bf16x8 al = *(const bf16x8*)&sAl[r * LDSP + quad * 8];
            #pragma unroll
            for (int m = 0; m < 2; ++m) {
                acc[m][n] = __builtin_amdgcn_mfma_f32_16x16x32_bf16(qh[m], ah, acc[m][n], 0, 0, 0);
                acc[m][n] = __builtin_amdgcn_mfma_f32_16x16x32_bf16(ql[m], ah, acc[m][n], 0, 0, 0);
                acc[m][n] = __builtin_amdgcn_mfma_f32_16x16x32_bf16(qh[m], al, acc[m][n], 0, 0, 0);
            }
        }
    }

    // ---- epilogue: online (m, l, s, argmax) per row within this 64-col slice
    int   cq[4]; float cw[4];
    #pragma unroll
    for (int n = 0; n < 4; ++n) {
        int col = j0 + wn * 64 + n * 16 + l16;
        cq[n] = qid[col];
        cw[n] = w[col];
    }
    const int slice = jb * 4 + wn;   // 0..63

    #pragma unroll
    for (int m = 0; m < 2; ++m) {
        #pragma unroll
        for (int reg = 0; reg < 4; ++reg) {
            const int row = i0 + wm * 32 + m * 16 + quad * 4 + reg;
            const int rq  = qid[row];

            float v[4];
            #pragma unroll
            for (int n = 0; n < 4; ++n) v[n] = acc[m][n][reg] * INV_T;

            float lm = fmaxf(fmaxf(v[0], v[1]), fmaxf(v[2], v[3]));
            float ll = expf(v[0] - lm) + expf(v[1] - lm) + expf(v[2] - lm) + expf(v[3] - lm);
            float ls = 0.f;
            #pragma unroll
            for (int n = 0; n < 4; ++n) ls += (cq[n] == rq) ? cw[n] * v[n] : 0.f;

            float bv = v[0];
            int   bi = j0 + wn * 64 + l16;
            #pragma unroll
            for (int n = 1; n < 4; ++n) {
                int c = j0 + wn * 64 + n * 16 + l16;
                if (v[n] > bv) { bv = v[n]; bi = c; }
            }

            // butterfly across the 16 lanes of this quad (xor 1,2,4,8)
            #pragma unroll
            for (int d = 1; d < 16; d <<= 1) {
                float om  = __shfl_xor(lm, d, 64);
                float ol  = __shfl_xor(ll, d, 64);
                float os  = __shfl_xor(ls, d, 64);
                float obv = __shfl_xor(bv, d, 64);
                int   obi = __shfl_xor(bi, d, 64);
                float nm = fmaxf(lm, om);
                ll = ll * expf(lm - nm) + ol * expf(om - nm);
                lm = nm;
                ls += os;
                if (obv > bv || (obv == bv && obi < bi)) { bv = obv; bi = obi; }
            }
            if (l16 == 0) {
                int idx = row * 64 + slice;
                Pm[idx] = lm; Pl[idx] = ll; Ps[idx] = ls;
                Pbv[idx] = bv; Pbi[idx] = bi;
            }
        }
    }
}

// ---------------------------------------------------------------------------
// Kernel 3: merge 64 slice-partials per row -> per_row loss term + acc flag
// ---------------------------------------------------------------------------
__global__ __launch_bounds__(256) void row_reduce_kernel(
    const float* __restrict__ Pm, const float* __restrict__ Pl,
    const float* __restrict__ Ps, const float* __restrict__ Pbv,
    const int* __restrict__ Pbi, const int* __restrict__ qid,
    float* __restrict__ per_row, float* __restrict__ ind)
{
    const int r    = blockIdx.x * 4 + (threadIdx.x >> 6);
    const int lane = threadIdx.x & 63;
    const int idx  = r * 64 + lane;

    float m = Pm[idx], l = Pl[idx], s = Ps[idx], bv = Pbv[idx];
    int   bi = Pbi[idx];

    #pragma unroll
    for (int d = 1; d < 64; d <<= 1) {
        float om  = __shfl_xor(m, d, 64);
        float ol  = __shfl_xor(l, d, 64);
        float os  = __shfl_xor(s, d, 64);
        float obv = __shfl_xor(bv, d, 64);
        int   obi = __shfl_xor(bi, d, 64);
        float nm = fmaxf(m, om);
        l = l * expf(m - nm) + ol * expf(om - nm);
        m = nm;
        s += os;
        if (obv > bv || (obv == bv && obi < bi)) { bv = obv; bi = obi; }
    }
    if (lane == 0) {
        per_row[r] = (m + logf(l)) - s;
        ind[r]     = (qid[bi] == qid[r]) ? 1.f : 0.f;
    }
}

// ---------------------------------------------------------------------------
// Kernel 4: final scalar reduction -> out[0]=loss, out[1]=acc
// ---------------------------------------------------------------------------
__global__ __launch_bounds__(1024) void final_kernel(
    const float* __restrict__ per_row, const float* __restrict__ ind,
    float* __restrict__ out)
{
    const int tid = threadIdx.x;
    float s1 = 0.f, s2 = 0.f;
    for (int i = tid; i < BATCH; i += 1024) { s1 += per_row[i]; s2 += ind[i]; }
    #pragma unroll
    for (int d = 1; d < 64; d <<= 1) {
        s1 += __shfl_xor(s1, d, 64);
        s2 += __shfl_xor(s2, d, 64);
    }
    __shared__ float r1[16], r2[16];
    if ((tid & 63) == 0) { r1[tid >> 6] = s1; r2[tid >> 6] = s2; }
    __syncthreads();
    if (tid == 0) {
        float t1 = 0.f, t2 = 0.f;
        #pragma unroll
        for (int i = 0; i < 16; ++i) { t1 += r1[i]; t2 += r2[i]; }
        out[0] = t1 / (float)BATCH;
        out[1] = t2 / (float)BATCH;
    }
}

// ---------------------------------------------------------------------------
extern "C" void kernel_launch(void* const* d_in, const int* in_sizes, int n_in,
                              void* d_out, int out_size, void* d_ws, size_t ws_size,
                              hipStream_t stream)
{
    const float* Q      = (const float*)d_in[0];
    const float* A      = (const float*)d_in[1];
    const int*   qid    = (const int*)d_in[2];
    const float* ranks  = (const float*)d_in[3];
    const float* scores = (const float*)d_in[4];
    float* out = (float*)d_out;

    // ws layout (floats): w[4096] | Pm,Pl,Ps,Pbv[4096*64] | Pbi[4096*64] (int)
    //                     | per_row[4096] | ind[4096]   (~5.3 MB total)
    float* w       = (float*)d_ws;
    float* Pm      = w + BATCH;
    float* Pl      = Pm + BATCH * 64;
    float* Ps      = Pl + BATCH * 64;
    float* Pbv     = Ps + BATCH * 64;
    int*   Pbi     = (int*)(Pbv + BATCH * 64);
    float* per_row = (float*)(Pbi + BATCH * 64);
    float* ind     = per_row + BATCH;

    compute_w_kernel<<<NGROUPS / 4, 256, 0, stream>>>(qid, ranks, scores, w);

    dim3 grid(BATCH / BJ, BATCH / BI);  // 16 x 32 = 512 blocks
    fused_simloss_kernel<<<grid, 1024, 0, stream>>>(Q, A, qid, w, Pm, Pl, Ps, Pbv, Pbi);

    row_reduce_kernel<<<BATCH / 4, 256, 0, stream>>>(Pm, Pl, Ps, Pbv, Pbi, qid, per_row, ind);

    final_kernel<<<1, 1024, 0, stream>>>(per_row, ind, out);
}

// Round 2
// 189.726 us; speedup vs baseline: 1.2590x; 1.2590x over previous
//
#include <hip/hip_runtime.h>
#include <hip/hip_bf16.h>
#include <math.h>

#define BATCH   4096
#define DIM     1024
#define NGROUPS 1024
#define INV_T   10.0f
#define RANK_W  0.1f
#define SCORE_W 0.01f

#define BI 128     // q rows per block
#define BJ 128     // a rows per block
#define KC 32      // k per stage

typedef float  floatx4 __attribute__((ext_vector_type(4)));
typedef __bf16 bf16x8  __attribute__((ext_vector_type(8)));
typedef __bf16 bf16x4  __attribute__((ext_vector_type(4)));

// async 16B/lane global->LDS: LDS dest is wave-uniform base + lane*16
#define ASYNC_COPY16(gptr, lptr)                                              \
    __builtin_amdgcn_global_load_lds(                                         \
        (const __attribute__((address_space(1))) void*)(gptr),                \
        (__attribute__((address_space(3))) void*)(lptr), 16, 0, 0)

// ---------------------------------------------------------------------------
// Kernel 1: prep. Blocks [0,1024): per-group weights. Blocks [1024,2048):
// fp32 -> bf16 conversion of Q and A into ws.
// ---------------------------------------------------------------------------
__global__ __launch_bounds__(256) void prep_kernel(
    const float* __restrict__ Q, const float* __restrict__ A,
    __bf16* __restrict__ Qb, __bf16* __restrict__ Ab,
    const int* __restrict__ qid, const float* __restrict__ ranks,
    const float* __restrict__ scores, float* __restrict__ w)
{
    const int tid = threadIdx.x;

    if (blockIdx.x >= NGROUPS) {
        // ---- convert part ----
        const int cid = blockIdx.x - NGROUPS;          // 0..1023
        const int n4  = BATCH * DIM / 4;               // 1M float4 per matrix
        for (int i = cid * 256 + tid; i < n4; i += 1024 * 256) {
            float4 v = ((const float4*)Q)[i];
            bf16x4 b;
            b[0] = (__bf16)v.x; b[1] = (__bf16)v.y;
            b[2] = (__bf16)v.z; b[3] = (__bf16)v.w;
            ((bf16x4*)Qb)[i] = b;
            v = ((const float4*)A)[i];
            b[0] = (__bf16)v.x; b[1] = (__bf16)v.y;
            b[2] = (__bf16)v.z; b[3] = (__bf16)v.w;
            ((bf16x4*)Ab)[i] = b;
        }
        return;
    }

    // ---- group-weight part: one block (256 threads) per group ----
    const int g = blockIdx.x, lane = tid & 63, wv = tid >> 6;
    __shared__ float rmax[4], rmin[4], rsum[4];

    float gmax = -INFINITY, gmin = INFINITY;
    for (int j = tid; j < BATCH; j += 256) {
        if (qid[j] == g) {
            float s = scores[j];
            gmax = fmaxf(gmax, s);
            gmin = fminf(gmin, s);
        }
    }
    #pragma unroll
    for (int d = 1; d < 64; d <<= 1) {
        gmax = fmaxf(gmax, __shfl_xor(gmax, d, 64));
        gmin = fminf(gmin, __shfl_xor(gmin, d, 64));
    }
    if (lane == 0) { rmax[wv] = gmax; rmin[wv] = gmin; }
    __syncthreads();
    gmax = fmaxf(fmaxf(rmax[0], rmax[1]), fmaxf(rmax[2], rmax[3]));
    gmin = fminf(fminf(rmin[0], rmin[1]), fminf(rmin[2], rmin[3]));
    const float denom     = gmax - gmin;
    const float inv_denom = (denom > 0.f) ? 1.f / denom : 0.f;

    float lsum = 0.f;
    for (int j = tid; j < BATCH; j += 256) {
        if (qid[j] == g) {
            float norm = (scores[j] - gmin) * inv_denom;
            float u = __expf(-RANK_W * ranks[j] + SCORE_W * norm);
            w[j] = u;             // unnormalized; this thread owns j
            lsum += u;
        }
    }
    #pragma unroll
    for (int d = 1; d < 64; d <<= 1) lsum += __shfl_xor(lsum, d, 64);
    if (lane == 0) rsum[wv] = lsum;
    __syncthreads();
    const float wsum = rsum[0] + rsum[1] + rsum[2] + rsum[3];
    const float inv  = (wsum > 0.f) ? 1.f / wsum : 0.f;
    for (int j = tid; j < BATCH; j += 256) {
        if (qid[j] == g) w[j] *= inv;
    }
}

// ---------------------------------------------------------------------------
// Kernel 2: fused sim = (Qb Ab^T)/T with online per-row (max, sumexp,
// weighted-sum, argmax) partials per 64-col slice.
// 128x128 block tile, 4 waves of 64x64, fragment-major LDS (conflict-free),
// global_load_lds 16B staging.
// ---------------------------------------------------------------------------
__global__ __launch_bounds__(256) void fused_simloss_kernel(
    const __bf16* __restrict__ Qb, const __bf16* __restrict__ Ab,
    const int* __restrict__ qid, const float* __restrict__ w,
    float* __restrict__ Pm, float* __restrict__ Pl, float* __restrict__ Ps,
    float* __restrict__ Pbv, int* __restrict__ Pbi)
{
    // fragment-major: fragment f (16 rows x 32 k) occupies [f*512, f*512+512)
    // elems; lane's 16B granule at f*512 + lane*8 holds row (lane&15),
    // k = (lane>>4)*8 .. +7  == exact MFMA operand layout.
    __shared__ __bf16 sQ[BI * KC];   // 8 fragments, 8 KB
    __shared__ __bf16 sA[BJ * KC];   // 8 fragments, 8 KB

    const int jb = blockIdx.x, ib = blockIdx.y;
    const int i0 = ib * BI, j0 = jb * BJ;
    const int tid = threadIdx.x, wid = tid >> 6, lane = tid & 63;
    const int wm = wid >> 1, wn = wid & 1;         // 2x2 wave grid, 64x64 tiles
    const int quad = lane >> 4, l16 = lane & 15;

    floatx4 acc[4][4];
    #pragma unroll
    for (int m = 0; m < 4; ++m)
        #pragma unroll
        for (int n = 0; n < 4; ++n)
            #pragma unroll
            for (int c = 0; c < 4; ++c) acc[m][n][c] = 0.f;

    // staging: wave `wid` owns Q-frags {2w,2w+1} and A-frags {2w,2w+1}
    const int lr = lane & 15;
    const int lk = (lane >> 4) * 8;
    const __bf16* qsrc0 = Qb + (size_t)(i0 + (wid * 2 + 0) * 16 + lr) * DIM + lk;
    const __bf16* qsrc1 = Qb + (size_t)(i0 + (wid * 2 + 1) * 16 + lr) * DIM + lk;
    const __bf16* asrc0 = Ab + (size_t)(j0 + (wid * 2 + 0) * 16 + lr) * DIM + lk;
    const __bf16* asrc1 = Ab + (size_t)(j0 + (wid * 2 + 1) * 16 + lr) * DIM + lk;
    __bf16* ldq0 = &sQ[(wid * 2 + 0) * 512];
    __bf16* ldq1 = &sQ[(wid * 2 + 1) * 512];
    __bf16* lda0 = &sA[(wid * 2 + 0) * 512];
    __bf16* lda1 = &sA[(wid * 2 + 1) * 512];

    for (int k0 = 0; k0 < DIM; k0 += KC) {
        __syncthreads();                       // prev iter's LDS reads done
        ASYNC_COPY16(qsrc0 + k0, ldq0);
        ASYNC_COPY16(qsrc1 + k0, ldq1);
        ASYNC_COPY16(asrc0 + k0, lda0);
        ASYNC_COPY16(asrc1 + k0, lda1);
        __syncthreads();                       // vmcnt(0) drain + barrier

        bf16x8 qf[4], af[4];
        #pragma unroll
        for (int mf = 0; mf < 4; ++mf)
            qf[mf] = *(const bf16x8*)&sQ[(wm * 4 + mf) * 512 + lane * 8];
        #pragma unroll
        for (int nf = 0; nf < 4; ++nf)
            af[nf] = *(const bf16x8*)&sA[(wn * 4 + nf) * 512 + lane * 8];
        #pragma unroll
        for (int nf = 0; nf < 4; ++nf)
            #pragma unroll
            for (int mf = 0; mf < 4; ++mf)
                acc[mf][nf] = __builtin_amdgcn_mfma_f32_16x16x32_bf16(
                    qf[mf], af[nf], acc[mf][nf], 0, 0, 0);
    }

    // ---- epilogue: online (m, l, s, argmax) per row within 64-col slice
    int cq[4]; float cw[4];
    #pragma unroll
    for (int n = 0; n < 4; ++n) {
        int col = j0 + wn * 64 + n * 16 + l16;
        cq[n] = qid[col];
        cw[n] = w[col];
    }
    const int slice = jb * 2 + wn;             // 0..63

    #pragma unroll
    for (int m = 0; m < 4; ++m) {
        #pragma unroll
        for (int reg = 0; reg < 4; ++reg) {
            const int row = i0 + wm * 64 + m * 16 + quad * 4 + reg;
            const int rq  = qid[row];

            float v[4];
            #pragma unroll
            for (int n = 0; n < 4; ++n) v[n] = acc[m][n][reg] * INV_T;

            float lm = fmaxf(fmaxf(v[0], v[1]), fmaxf(v[2], v[3]));
            float ll = __expf(v[0] - lm) + __expf(v[1] - lm) +
                       __expf(v[2] - lm) + __expf(v[3] - lm);
            float ls = 0.f;
            #pragma unroll
            for (int n = 0; n < 4; ++n) ls += (cq[n] == rq) ? cw[n] * v[n] : 0.f;

            float bv = v[0];
            int   bi = j0 + wn * 64 + l16;
            #pragma unroll
            for (int n = 1; n < 4; ++n) {
                int c = j0 + wn * 64 + n * 16 + l16;
                if (v[n] > bv) { bv = v[n]; bi = c; }
            }

            #pragma unroll
            for (int d = 1; d < 16; d <<= 1) {
                float om  = __shfl_xor(lm, d, 64);
                float ol  = __shfl_xor(ll, d, 64);
                float os  = __shfl_xor(ls, d, 64);
                float obv = __shfl_xor(bv, d, 64);
                int   obi = __shfl_xor(bi, d, 64);
                float nm = fmaxf(lm, om);
                ll = ll * __expf(lm - nm) + ol * __expf(om - nm);
                lm = nm;
                ls += os;
                if (obv > bv || (obv == bv && obi < bi)) { bv = obv; bi = obi; }
            }
            if (l16 == 0) {
                int idx = row * 64 + slice;
                Pm[idx] = lm; Pl[idx] = ll; Ps[idx] = ls;
                Pbv[idx] = bv; Pbi[idx] = bi;
            }
        }
    }
}

// ---------------------------------------------------------------------------
// Kernel 3: merge 64 slice-partials per row -> per_row loss term + acc flag
// ---------------------------------------------------------------------------
__global__ __launch_bounds__(256) void row_reduce_kernel(
    const float* __restrict__ Pm, const float* __restrict__ Pl,
    const float* __restrict__ Ps, const float* __restrict__ Pbv,
    const int* __restrict__ Pbi, const int* __restrict__ qid,
    float* __restrict__ per_row, float* __restrict__ ind)
{
    const int r    = blockIdx.x * 4 + (threadIdx.x >> 6);
    const int lane = threadIdx.x & 63;
    const int idx  = r * 64 + lane;

    float m = Pm[idx], l = Pl[idx], s = Ps[idx], bv = Pbv[idx];
    int   bi = Pbi[idx];

    #pragma unroll
    for (int d = 1; d < 64; d <<= 1) {
        float om  = __shfl_xor(m, d, 64);
        float ol  = __shfl_xor(l, d, 64);
        float os  = __shfl_xor(s, d, 64);
        float obv = __shfl_xor(bv, d, 64);
        int   obi = __shfl_xor(bi, d, 64);
        float nm = fmaxf(m, om);
        l = l * __expf(m - nm) + ol * __expf(om - nm);
        m = nm;
        s += os;
        if (obv > bv || (obv == bv && obi < bi)) { bv = obv; bi = obi; }
    }
    if (lane == 0) {
        per_row[r] = (m + logf(l)) - s;
        ind[r]     = (qid[bi] == qid[r]) ? 1.f : 0.f;
    }
}

// ---------------------------------------------------------------------------
// Kernel 4: final scalar reduction -> out[0]=loss, out[1]=acc
// ---------------------------------------------------------------------------
__global__ __launch_bounds__(1024) void final_kernel(
    const float* __restrict__ per_row, const float* __restrict__ ind,
    float* __restrict__ out)
{
    const int tid = threadIdx.x;
    float s1 = 0.f, s2 = 0.f;
    for (int i = tid; i < BATCH; i += 1024) { s1 += per_row[i]; s2 += ind[i]; }
    #pragma unroll
    for (int d = 1; d < 64; d <<= 1) {
        s1 += __shfl_xor(s1, d, 64);
        s2 += __shfl_xor(s2, d, 64);
    }
    __shared__ float r1[16], r2[16];
    if ((tid & 63) == 0) { r1[tid >> 6] = s1; r2[tid >> 6] = s2; }
    __syncthreads();
    if (tid == 0) {
        float t1 = 0.f, t2 = 0.f;
        #pragma unroll
        for (int i = 0; i < 16; ++i) { t1 += r1[i]; t2 += r2[i]; }
        out[0] = t1 / (float)BATCH;
        out[1] = t2 / (float)BATCH;
    }
}

// ---------------------------------------------------------------------------
extern "C" void kernel_launch(void* const* d_in, const int* in_sizes, int n_in,
                              void* d_out, int out_size, void* d_ws, size_t ws_size,
                              hipStream_t stream)
{
    const float* Q      = (const float*)d_in[0];
    const float* A      = (const float*)d_in[1];
    const int*   qid    = (const int*)d_in[2];
    const float* ranks  = (const float*)d_in[3];
    const float* scores = (const float*)d_in[4];
    float* out = (float*)d_out;

    // ws layout: Qb[4M bf16]=8MB | Ab[4M bf16]=8MB | w[4096] |
    //            Pm,Pl,Ps,Pbv[262144] | Pbi[262144] | per_row[4096] | ind[4096]
    __bf16* Qb = (__bf16*)d_ws;
    __bf16* Ab = Qb + (size_t)BATCH * DIM;
    float* w       = (float*)(Ab + (size_t)BATCH * DIM);
    float* Pm      = w + BATCH;
    float* Pl      = Pm + BATCH * 64;
    float* Ps      = Pl + BATCH * 64;
    float* Pbv     = Ps + BATCH * 64;
    int*   Pbi     = (int*)(Pbv + BATCH * 64);
    float* per_row = (float*)(Pbi + BATCH * 64);
    float* ind     = per_row + BATCH;

    prep_kernel<<<2048, 256, 0, stream>>>(Q, A, Qb, Ab, qid, ranks, scores, w);

    dim3 grid(BATCH / BJ, BATCH / BI);  // 32 x 32 = 1024 blocks
    fused_simloss_kernel<<<grid, 256, 0, stream>>>(Qb, Ab, qid, w, Pm, Pl, Ps, Pbv, Pbi);

    row_reduce_kernel<<<BATCH / 4, 256, 0, stream>>>(Pm, Pl, Ps, Pbv, Pbi, qid, per_row, ind);

    final_kernel<<<1, 1024, 0, stream>>>(per_row, ind, out);
}

// Round 3
// 162.521 us; speedup vs baseline: 1.4697x; 1.1674x over previous
//
#include <hip/hip_runtime.h>
#include <hip/hip_bf16.h>
#include <math.h>

#define BATCH   4096
#define DIM     1024
#define NGROUPS 1024
#define INV_T   10.0f
#define RANK_W  0.1f
#define SCORE_W 0.01f

#define BI 128       // q rows per block
#define BJ 256       // a rows per block
#define KC 32        // k per stage
#define NFRAG_Q (BI/16)          // 8
#define NFRAG   (BI/16 + BJ/16)  // 24 fragments per stage
#define FRAG_ELEMS 512           // 16 rows x 32 k bf16

typedef float  floatx4 __attribute__((ext_vector_type(4)));
typedef __bf16 bf16x8  __attribute__((ext_vector_type(8)));
typedef __bf16 bf16x4  __attribute__((ext_vector_type(4)));

// async 16B/lane global->LDS: LDS dest is wave-uniform base + lane*16
#define ASYNC_COPY16(gptr, lptr)                                              \
    __builtin_amdgcn_global_load_lds(                                         \
        (const __attribute__((address_space(1))) void*)(gptr),                \
        (__attribute__((address_space(3))) void*)(lptr), 16, 0, 0)

// ---------------------------------------------------------------------------
// Kernel 1: prep. Blocks [0,1024): per-group weights. Blocks [1024,2048):
// fp32 -> bf16 conversion of Q and A into ws.
// ---------------------------------------------------------------------------
__global__ __launch_bounds__(256) void prep_kernel(
    const float* __restrict__ Q, const float* __restrict__ A,
    __bf16* __restrict__ Qb, __bf16* __restrict__ Ab,
    const int* __restrict__ qid, const float* __restrict__ ranks,
    const float* __restrict__ scores, float* __restrict__ w)
{
    const int tid = threadIdx.x;

    if (blockIdx.x >= NGROUPS) {
        const int cid = blockIdx.x - NGROUPS;          // 0..1023
        const int n4  = BATCH * DIM / 4;               // 1M float4 per matrix
        for (int i = cid * 256 + tid; i < n4; i += 1024 * 256) {
            float4 v = ((const float4*)Q)[i];
            bf16x4 b;
            b[0] = (__bf16)v.x; b[1] = (__bf16)v.y;
            b[2] = (__bf16)v.z; b[3] = (__bf16)v.w;
            ((bf16x4*)Qb)[i] = b;
            v = ((const float4*)A)[i];
            b[0] = (__bf16)v.x; b[1] = (__bf16)v.y;
            b[2] = (__bf16)v.z; b[3] = (__bf16)v.w;
            ((bf16x4*)Ab)[i] = b;
        }
        return;
    }

    // ---- group-weight part: one block (256 threads) per group ----
    const int g = blockIdx.x, lane = tid & 63, wv = tid >> 6;
    __shared__ float rmax[4], rmin[4], rsum[4];

    float gmax = -INFINITY, gmin = INFINITY;
    for (int j = tid; j < BATCH; j += 256) {
        if (qid[j] == g) {
            float s = scores[j];
            gmax = fmaxf(gmax, s);
            gmin = fminf(gmin, s);
        }
    }
    #pragma unroll
    for (int d = 1; d < 64; d <<= 1) {
        gmax = fmaxf(gmax, __shfl_xor(gmax, d, 64));
        gmin = fminf(gmin, __shfl_xor(gmin, d, 64));
    }
    if (lane == 0) { rmax[wv] = gmax; rmin[wv] = gmin; }
    __syncthreads();
    gmax = fmaxf(fmaxf(rmax[0], rmax[1]), fmaxf(rmax[2], rmax[3]));
    gmin = fminf(fminf(rmin[0], rmin[1]), fminf(rmin[2], rmin[3]));
    const float denom     = gmax - gmin;
    const float inv_denom = (denom > 0.f) ? 1.f / denom : 0.f;

    float lsum = 0.f;
    for (int j = tid; j < BATCH; j += 256) {
        if (qid[j] == g) {
            float norm = (scores[j] - gmin) * inv_denom;
            float u = __expf(-RANK_W * ranks[j] + SCORE_W * norm);
            w[j] = u;             // unnormalized; this thread owns j
            lsum += u;
        }
    }
    #pragma unroll
    for (int d = 1; d < 64; d <<= 1) lsum += __shfl_xor(lsum, d, 64);
    if (lane == 0) rsum[wv] = lsum;
    __syncthreads();
    const float wsum = rsum[0] + rsum[1] + rsum[2] + rsum[3];
    const float inv  = (wsum > 0.f) ? 1.f / wsum : 0.f;
    for (int j = tid; j < BATCH; j += 256) {
        if (qid[j] == g) w[j] *= inv;
    }
}

// ---------------------------------------------------------------------------
// Kernel 2: fused sim = (Qb Ab^T)/T with online per-row (max, sumexp,
// weighted-sum, argmax) partials per 64-col slice.
// 128x256 block tile, 8 waves of 64x64, fragment-major LDS (0 conflicts),
// DOUBLE-BUFFERED global_load_lds with prefetch distance 1, 1 barrier/iter.
// ---------------------------------------------------------------------------
__global__ __launch_bounds__(512, 4) void fused_simloss_kernel(
    const __bf16* __restrict__ Qb, const __bf16* __restrict__ Ab,
    const int* __restrict__ qid, const float* __restrict__ w,
    float* __restrict__ Pm, float* __restrict__ Pl, float* __restrict__ Ps,
    float* __restrict__ Pbv, int* __restrict__ Pbi)
{
    // fragment-major: fragment f (16 rows x 32 k) at [f*512, f*512+512);
    // lane's 16B granule at f*512 + lane*8 holds row (lane&15),
    // k = (lane>>4)*8..+7 == exact MFMA operand layout. Frags 0..7 = Q,
    // frags 8..23 = A. Two buffers for prefetch.
    __shared__ __bf16 sbuf[2][NFRAG * FRAG_ELEMS];   // 2 x 24 KB

    const int jb = blockIdx.x, ib = blockIdx.y;
    const int i0 = ib * BI, j0 = jb * BJ;
    const int tid = threadIdx.x, wid = tid >> 6, lane = tid & 63;
    const int wm = wid >> 2, wn = wid & 3;      // 2x4 wave grid, 64x64 tiles
    const int quad = lane >> 4, l16 = lane & 15;

    floatx4 acc[4][4];
    #pragma unroll
    for (int m = 0; m < 4; ++m)
        #pragma unroll
        for (int n = 0; n < 4; ++n)
            #pragma unroll
            for (int c = 0; c < 4; ++c) acc[m][n][c] = 0.f;

    // staging: wave `wid` owns fragments f = wid*3 .. wid*3+2
    const int lr = lane & 15;
    const int lk = (lane >> 4) * 8;
    const __bf16* src[3];
    #pragma unroll
    for (int c = 0; c < 3; ++c) {
        const int f = wid * 3 + c;
        src[c] = (f < NFRAG_Q)
               ? Qb + (size_t)(i0 + f * 16 + lr) * DIM + lk
               : Ab + (size_t)(j0 + (f - NFRAG_Q) * 16 + lr) * DIM + lk;
    }

    #define STAGE(buf, k0)                                                    \
        do {                                                                  \
            _Pragma("unroll")                                                 \
            for (int c = 0; c < 3; ++c)                                       \
                ASYNC_COPY16(src[c] + (k0),                                   \
                             &sbuf[buf][(wid * 3 + c) * FRAG_ELEMS]);         \
        } while (0)

    STAGE(0, 0);   // prefetch stage 0

    for (int t = 0; t < DIM / KC; ++t) {
        __syncthreads();   // drains buf[t&1] copies (issued 1 iter ago) and
                           // orders prev reads of buf[(t+1)&1] before rewrite
        if (t + 1 < DIM / KC) STAGE((t + 1) & 1, (t + 1) * KC);

        const __bf16* cur = sbuf[t & 1];
        bf16x8 qf[4], af[4];
        #pragma unroll
        for (int mf = 0; mf < 4; ++mf)
            qf[mf] = *(const bf16x8*)&cur[(wm * 4 + mf) * FRAG_ELEMS + lane * 8];
        #pragma unroll
        for (int nf = 0; nf < 4; ++nf)
            af[nf] = *(const bf16x8*)&cur[(NFRAG_Q + wn * 4 + nf) * FRAG_ELEMS + lane * 8];
        #pragma unroll
        for (int nf = 0; nf < 4; ++nf)
            #pragma unroll
            for (int mf = 0; mf < 4; ++mf)
                acc[mf][nf] = __builtin_amdgcn_mfma_f32_16x16x32_bf16(
                    qf[mf], af[nf], acc[mf][nf], 0, 0, 0);
    }
    #undef STAGE

    // ---- epilogue: online (m, l, s, argmax) per row within 64-col slice
    int cq[4]; float cw[4];
    #pragma unroll
    for (int n = 0; n < 4; ++n) {
        int col = j0 + wn * 64 + n * 16 + l16;
        cq[n] = qid[col];
        cw[n] = w[col];
    }
    const int slice = jb * 4 + wn;             // 0..63

    #pragma unroll
    for (int m = 0; m < 4; ++m) {
        #pragma unroll
        for (int reg = 0; reg < 4; ++reg) {
            const int row = i0 + wm * 64 + m * 16 + quad * 4 + reg;
            const int rq  = qid[row];

            float v[4];
            #pragma unroll
            for (int n = 0; n < 4; ++n) v[n] = acc[m][n][reg] * INV_T;

            float lm = fmaxf(fmaxf(v[0], v[1]), fmaxf(v[2], v[3]));
            float ll = __expf(v[0] - lm) + __expf(v[1] - lm) +
                       __expf(v[2] - lm) + __expf(v[3] - lm);
            float ls = 0.f;
            #pragma unroll
            for (int n = 0; n < 4; ++n) ls += (cq[n] == rq) ? cw[n] * v[n] : 0.f;

            float bv = v[0];
            int   bi = j0 + wn * 64 + l16;
            #pragma unroll
            for (int n = 1; n < 4; ++n) {
                int c = j0 + wn * 64 + n * 16 + l16;
                if (v[n] > bv) { bv = v[n]; bi = c; }
            }

            #pragma unroll
            for (int d = 1; d < 16; d <<= 1) {
                float om  = __shfl_xor(lm, d, 64);
                float ol  = __shfl_xor(ll, d, 64);
                float os  = __shfl_xor(ls, d, 64);
                float obv = __shfl_xor(bv, d, 64);
                int   obi = __shfl_xor(bi, d, 64);
                float nm = fmaxf(lm, om);
                ll = ll * __expf(lm - nm) + ol * __expf(om - nm);
                lm = nm;
                ls += os;
                if (obv > bv || (obv == bv && obi < bi)) { bv = obv; bi = obi; }
            }
            if (l16 == 0) {
                int idx = row * 64 + slice;
                Pm[idx] = lm; Pl[idx] = ll; Ps[idx] = ls;
                Pbv[idx] = bv; Pbi[idx] = bi;
            }
        }
    }
}

// ---------------------------------------------------------------------------
// Kernel 3: merge 64 slice-partials per row -> per_row loss term + acc flag
// ---------------------------------------------------------------------------
__global__ __launch_bounds__(256) void row_reduce_kernel(
    const float* __restrict__ Pm, const float* __restrict__ Pl,
    const float* __restrict__ Ps, const float* __restrict__ Pbv,
    const int* __restrict__ Pbi, const int* __restrict__ qid,
    float* __restrict__ per_row, float* __restrict__ ind)
{
    const int r    = blockIdx.x * 4 + (threadIdx.x >> 6);
    const int lane = threadIdx.x & 63;
    const int idx  = r * 64 + lane;

    float m = Pm[idx], l = Pl[idx], s = Ps[idx], bv = Pbv[idx];
    int   bi = Pbi[idx];

    #pragma unroll
    for (int d = 1; d < 64; d <<= 1) {
        float om  = __shfl_xor(m, d, 64);
        float ol  = __shfl_xor(l, d, 64);
        float os  = __shfl_xor(s, d, 64);
        float obv = __shfl_xor(bv, d, 64);
        int   obi = __shfl_xor(bi, d, 64);
        float nm = fmaxf(m, om);
        l = l * __expf(m - nm) + ol * __expf(om - nm);
        m = nm;
        s += os;
        if (obv > bv || (obv == bv && obi < bi)) { bv = obv; bi = obi; }
    }
    if (lane == 0) {
        per_row[r] = (m + logf(l)) - s;
        ind[r]     = (qid[bi] == qid[r]) ? 1.f : 0.f;
    }
}

// ---------------------------------------------------------------------------
// Kernel 4: final scalar reduction -> out[0]=loss, out[1]=acc
// ---------------------------------------------------------------------------
__global__ __launch_bounds__(1024) void final_kernel(
    const float* __restrict__ per_row, const float* __restrict__ ind,
    float* __restrict__ out)
{
    const int tid = threadIdx.x;
    float s1 = 0.f, s2 = 0.f;
    for (int i = tid; i < BATCH; i += 1024) { s1 += per_row[i]; s2 += ind[i]; }
    #pragma unroll
    for (int d = 1; d < 64; d <<= 1) {
        s1 += __shfl_xor(s1, d, 64);
        s2 += __shfl_xor(s2, d, 64);
    }
    __shared__ float r1[16], r2[16];
    if ((tid & 63) == 0) { r1[tid >> 6] = s1; r2[tid >> 6] = s2; }
    __syncthreads();
    if (tid == 0) {
        float t1 = 0.f, t2 = 0.f;
        #pragma unroll
        for (int i = 0; i < 16; ++i) { t1 += r1[i]; t2 += r2[i]; }
        out[0] = t1 / (float)BATCH;
        out[1] = t2 / (float)BATCH;
    }
}

// ---------------------------------------------------------------------------
extern "C" void kernel_launch(void* const* d_in, const int* in_sizes, int n_in,
                              void* d_out, int out_size, void* d_ws, size_t ws_size,
                              hipStream_t stream)
{
    const float* Q      = (const float*)d_in[0];
    const float* A      = (const float*)d_in[1];
    const int*   qid    = (const int*)d_in[2];
    const float* ranks  = (const float*)d_in[3];
    const float* scores = (const float*)d_in[4];
    float* out = (float*)d_out;

    // ws layout: Qb[4M bf16]=8MB | Ab[4M bf16]=8MB | w[4096] |
    //            Pm,Pl,Ps,Pbv[262144] | Pbi[262144] | per_row[4096] | ind[4096]
    __bf16* Qb = (__bf16*)d_ws;
    __bf16* Ab = Qb + (size_t)BATCH * DIM;
    float* w       = (float*)(Ab + (size_t)BATCH * DIM);
    float* Pm      = w + BATCH;
    float* Pl      = Pm + BATCH * 64;
    float* Ps      = Pl + BATCH * 64;
    float* Pbv     = Ps + BATCH * 64;
    int*   Pbi     = (int*)(Pbv + BATCH * 64);
    float* per_row = (float*)(Pbi + BATCH * 64);
    float* ind     = per_row + BATCH;

    prep_kernel<<<2048, 256, 0, stream>>>(Q, A, Qb, Ab, qid, ranks, scores, w);

    dim3 grid(BATCH / BJ, BATCH / BI);  // 16 x 32 = 512 blocks
    fused_simloss_kernel<<<grid, 512, 0, stream>>>(Qb, Ab, qid, w, Pm, Pl, Ps, Pbv, Pbi);

    row_reduce_kernel<<<BATCH / 4, 256, 0, stream>>>(Pm, Pl, Ps, Pbv, Pbi, qid, per_row, ind);

    final_kernel<<<1, 1024, 0, stream>>>(per_row, ind, out);
}